// Round 2
// baseline (277572.461 us; speedup 1.0000x reference)
//
#include <hip/hip_runtime.h>
#include <hip/hip_bf16.h>

// Problem: T=8192 steps, D_IN=2048, D=512 dense, H=512 cell, A=18 actions.
// out = concat(policy [T,18], value [T,1], hT [1,512]) fp32, 156160 elems.
//
// R1: scan is latency-bound on AGENT-scope (sc0+sc1 = L3-coherent) h-exchange
// across 8 XCDs (3860 cyc/step, VALUBusy 2.6%). Pin all 32 worker WGs to ONE
// XCD (HW_REG_XCC_ID claim election) and run the exchange sc0-only
// (L1-bypass, L2-coherent within the XCD). FAIL-SAFE: publishers ALSO mirror
// every h to hbuf2 via RELAXED AGENT atomics (fire-and-forget); consumers
// probe hbuf2 at AGENT scope every 256 spins. If the single-XCD fast path
// breaks for ANY reason, the kernel degrades to a correct baseline-speed run
// instead of hanging (R0's container death may have been exactly that hang).

#define T_STEPS 8192
#define DIN 2048
#define DD 512
#define HHH 512
#define AACT 18
#define H3 1536
#define NWG 32          // worker WGs; each owns 16 rows of h
#define SCAN_GRID 1024  // over-launch; non-elected WGs exit immediately

typedef __attribute__((ext_vector_type(8))) short short8;
typedef __attribute__((ext_vector_type(4))) float f32x4;

// ---------------------------------------------------------------- casts
__global__ void cast_f32_bf16(const float* __restrict__ in,
                              __hip_bfloat16* __restrict__ out, int n)
{
    int i = blockIdx.x * 256 + threadIdx.x;
    if (i < n) out[i] = __float2bfloat16(in[i]);
}

// ctl[0]=claim counter, ctl[1]=elected XCD (-1 = none), ctl[2]=abort flag
__global__ void init_ctl(int* ctl) { ctl[0] = 0; ctl[1] = -1; ctl[2] = 0; }

// ---------------------------------------------------------------- GEMM
// C[M,N] = act(A[M,K] @ B[K,N] + bias). A either fp32 (cast on stage) or bf16.
// Block 256 (4 waves), tile 64x64, K-tile 32.
// MFMA 16x16x32 bf16: D: col=lane&15, row=quad*4+reg (verified m89/m91).
__global__ __launch_bounds__(256) void gemm_bf16(
    const float* __restrict__ A32, const __hip_bfloat16* __restrict__ A16,
    const __hip_bfloat16* __restrict__ B, const float* __restrict__ bias,
    __hip_bfloat16* __restrict__ Cb, float* __restrict__ Cf,
    int M, int N, int K, int relu)
{
    const int m0 = blockIdx.x * 64;
    const int n0 = blockIdx.y * 64;
    const int t  = threadIdx.x;
    const int wave = t >> 6;
    const int lane = t & 63;
    const int quad = lane >> 4;
    const int l16  = lane & 15;

    __shared__ __align__(16) __hip_bfloat16 As[64 * 40];
    __shared__ __align__(16) __hip_bfloat16 Bs[64 * 40];

    f32x4 acc[4];
#pragma unroll
    for (int c = 0; c < 4; ++c) acc[c] = (f32x4){0.f, 0.f, 0.f, 0.f};

    const int ar = t >> 2, akc = (t & 3) * 8;
    const int bk = t >> 3, bn  = (t & 7) * 8;

    for (int kb = 0; kb < K; kb += 32) {
        if (A32) {
            const float* src = A32 + (size_t)(m0 + ar) * K + kb + akc;
            float4 f0 = *(const float4*)(src);
            float4 f1 = *(const float4*)(src + 4);
            union { short8 v; __hip_bfloat16 h[8]; } u;
            u.h[0] = __float2bfloat16(f0.x); u.h[1] = __float2bfloat16(f0.y);
            u.h[2] = __float2bfloat16(f0.z); u.h[3] = __float2bfloat16(f0.w);
            u.h[4] = __float2bfloat16(f1.x); u.h[5] = __float2bfloat16(f1.y);
            u.h[6] = __float2bfloat16(f1.z); u.h[7] = __float2bfloat16(f1.w);
            *(short8*)&As[ar * 40 + akc] = u.v;
        } else {
            const __hip_bfloat16* src = A16 + (size_t)(m0 + ar) * K + kb + akc;
            *(short8*)&As[ar * 40 + akc] = *(const short8*)src;
        }
        {
            const __hip_bfloat16* src = B + (size_t)(kb + bk) * N + n0 + bn;
            short8 v = *(const short8*)src;
            const __hip_bfloat16* vh = (const __hip_bfloat16*)&v;
#pragma unroll
            for (int i = 0; i < 8; ++i) Bs[(bn + i) * 40 + bk] = vh[i];
        }
        __syncthreads();

        short8 a = *(const short8*)&As[(wave * 16 + l16) * 40 + quad * 8];
#pragma unroll
        for (int c = 0; c < 4; ++c) {
            short8 b = *(const short8*)&Bs[(c * 16 + l16) * 40 + quad * 8];
            acc[c] = __builtin_amdgcn_mfma_f32_16x16x32_bf16(a, b, acc[c], 0, 0, 0);
        }
        __syncthreads();
    }

#pragma unroll
    for (int c = 0; c < 4; ++c) {
        const int col = n0 + c * 16 + l16;
        const float bb = bias ? bias[col] : 0.f;
#pragma unroll
        for (int r = 0; r < 4; ++r) {
            const int row = m0 + wave * 16 + quad * 4 + r;
            float v = acc[c][r] + bb;
            if (relu) v = fmaxf(v, 0.f);
            if (Cb) Cb[(size_t)row * N + col] = __float2bfloat16(v);
            if (Cf) Cf[(size_t)row * N + col] = v;
        }
    }
}

// ---------------------------------------------------------------- GRU scan
// 32 persistent worker WGs x 256 threads, pinned to one XCD via XCC_ID claim
// election. waves_per_eu(1,1) => 1 WG/CU; 32 workers = the XCD's 32 CUs.
// h exchange: tagged {f32 val, u32 step} 8B slots, double-buffered by step
// parity. Fast path sc0-only (XCD-L2 coherent); mirror path AGENT atomics
// (L3 coherent) probed every 256 spins. Tag+value travel in one aligned 8B
// store => no fences. Slot reuse distance is 2 steps and a publisher cannot
// run ahead of any consumer by 2 (it must consume h_{s+1} first), so tags
// are race-free. 0xAA poison never matches a tag in [1,8192].
__global__ __launch_bounds__(256)
__attribute__((amdgpu_waves_per_eu(1, 1)))
void scan_kernel(
    const float* __restrict__ X,            // [T][1536] = z@Wg + bg[0]
    const float* __restrict__ Ug,           // [512][1536]
    const float* __restrict__ bg,           // [2][1536]; row 1 = recurrent bias
    const float* __restrict__ h0,           // [512] prev_hidden
    float* __restrict__ seq,                // [T][512]
    unsigned long long* __restrict__ hbuf,  // [2][512] tagged h, sc0 fast path
    unsigned long long* __restrict__ hbuf2, // [2][512] tagged h, AGENT mirror
    float* __restrict__ hT,                 // [512] -> d_out tail
    int* __restrict__ ctl)                  // {claim, elected_xcd, abort}
{
    __shared__ int claim_s;
    __shared__ int wg_abort;
    const int t = threadIdx.x;

    if (t == 0) {
        unsigned int xcc;
        asm volatile("s_getreg_b32 %0, hwreg(HW_REG_XCC_ID)" : "=s"(xcc));
        int prev = atomicCAS(ctl + 1, -1, (int)xcc);
        unsigned int target = (prev == -1) ? xcc : (unsigned int)prev;
        int slot = -1;
        if (xcc == target) {
            slot = atomicAdd(ctl + 0, 1);
            if (slot >= NWG) slot = -1;
        }
        claim_s = slot;
        wg_abort = 0;
    }
    __syncthreads();
    const int wg = claim_s;
    if (wg < 0) return;

    const int jl = t >> 4;
    const int kp = t & 15;
    const int j  = wg * 16 + jl;
    const int k0 = kp * 32;

    // double-buffered h stage; row stride 36 words = 144B (16B aligned;
    // b128 reads across 16 kp-lanes alias banks 2-way = free per m136)
    __shared__ __align__(16) float h_lds[2][16 * 36];

    float wz[32], wr[32], wh[32];
#pragma unroll
    for (int m = 0; m < 32; ++m) {
        const float* row = Ug + (size_t)(k0 + m) * H3;
        wz[m] = row[j];
        wr[m] = row[512 + j];
        wh[m] = row[1024 + j];
    }
    // pin all 96 weights into AGPRs: guaranteed register residency for the
    // whole step loop (no scratch spill path exists for "a"-pinned values)
#pragma unroll
    for (int m = 0; m < 32; ++m) {
        asm volatile("" : "+a"(wz[m]), "+a"(wr[m]), "+a"(wh[m]));
    }

    const float* brec = bg + H3;
    const float bz = brec[j], brr = brec[512 + j], bh = brec[1024 + j];
    float hj = h0[j];  // my h element (kp==0 lanes)

    // staging slots for this thread
    const int k1 = t, k2 = t + 256;
    const int a1 = (k1 >> 5) * 36 + (k1 & 31);
    const int a2 = (k2 >> 5) * 36 + (k2 & 31);

    // prefetch X[0]
    float xz = 0.f, xr = 0.f, xh = 0.f;
    if (kp == 0) { xz = X[j]; xr = X[512 + j]; xh = X[1024 + j]; }

    for (int s = 0; s < T_STEPS; ++s) {
        float* hl = h_lds[s & 1];

        // ---- prefetch X[s+1] FIRST: the load retires under the spin
        float nxz = 0.f, nxr = 0.f, nxh = 0.f;
        if (kp == 0 && s + 1 < T_STEPS) {
            const float* Xs = X + (size_t)(s + 1) * H3;
            nxz = Xs[j]; nxr = Xs[512 + j]; nxh = Xs[1024 + j];
        }

        // ---- acquire h_s
        if (s == 0) {
            hl[a1] = h0[k1];
            hl[a2] = h0[k2];
        } else {
            const unsigned long long* f1 = hbuf  + ((size_t)(s & 1) << 9);
            const unsigned long long* m1 = hbuf2 + ((size_t)(s & 1) << 9);
            unsigned long long v1 = 0, v2 = 0;
            bool ok1 = false, ok2 = false;
            int guard = 0, bail = 0;
            do {
                if ((++guard & 0xFF) == 0) {
                    // slow path: AGENT mirror probe + abort/dead-man check
                    v1 = __hip_atomic_load(m1 + k1, __ATOMIC_RELAXED, __HIP_MEMORY_SCOPE_AGENT);
                    v2 = __hip_atomic_load(m1 + k2, __ATOMIC_RELAXED, __HIP_MEMORY_SCOPE_AGENT);
                    int ab = __hip_atomic_load(ctl + 2, __ATOMIC_RELAXED, __HIP_MEMORY_SCOPE_AGENT);
                    if (ab || guard > (1 << 22)) { bail = 1; break; }
                } else {
                    // fast path: sc0 loads served by our XCD's L2
                    asm volatile("global_load_dwordx2 %0, %2, off sc0\n\t"
                                 "global_load_dwordx2 %1, %3, off sc0\n\t"
                                 "s_waitcnt vmcnt(0)"
                                 : "=&v"(v1), "=&v"(v2)
                                 : "v"(f1 + k1), "v"(f1 + k2) : "memory");
                }
                ok1 = (unsigned)(v1 >> 32) == (unsigned)s;
                ok2 = (unsigned)(v2 >> 32) == (unsigned)s;
            } while (!(ok1 && ok2));
            if (bail) wg_abort = 1;
            hl[a1] = __uint_as_float((unsigned)v1);
            hl[a2] = __uint_as_float((unsigned)v2);
        }
        __syncthreads();
        if (wg_abort) {            // collective fail-fast (no barrier split)
            if (t == 0)
                __hip_atomic_store(ctl + 2, 1, __ATOMIC_RELAXED, __HIP_MEMORY_SCOPE_AGENT);
            return;
        }

        // ---- partial matvec: 32 k-values x 3 gate columns
        float accz = 0.f, accr = 0.f, acch = 0.f;
        const float* hb = &hl[kp * 36];
#pragma unroll
        for (int m = 0; m < 32; m += 4) {
            float4 hv = *(const float4*)(hb + m);
            accz = fmaf(hv.x, wz[m    ], accz);
            accz = fmaf(hv.y, wz[m + 1], accz);
            accz = fmaf(hv.z, wz[m + 2], accz);
            accz = fmaf(hv.w, wz[m + 3], accz);
            accr = fmaf(hv.x, wr[m    ], accr);
            accr = fmaf(hv.y, wr[m + 1], accr);
            accr = fmaf(hv.z, wr[m + 2], accr);
            accr = fmaf(hv.w, wr[m + 3], accr);
            acch = fmaf(hv.x, wh[m    ], acch);
            acch = fmaf(hv.y, wh[m + 1], acch);
            acch = fmaf(hv.z, wh[m + 2], acch);
            acch = fmaf(hv.w, wh[m + 3], acch);
        }
        // reduce across the 16 kp lanes (contiguous in-wave)
#pragma unroll
        for (int off = 8; off; off >>= 1) {
            accz += __shfl_down(accz, off, 16);
            accr += __shfl_down(accr, off, 16);
            acch += __shfl_down(acch, off, 16);
        }

        if (kp == 0) {
            const float rz = accz + bz, rr = accr + brr, rh = acch + bh;
            const float zt = 1.f / (1.f + __expf(-(xz + rz)));
            const float rt = 1.f / (1.f + __expf(-(xr + rr)));
            const float hc = 1.f / (1.f + __expf(-(xh + rt * rh)));
            const float hn = zt * hj + (1.f - zt) * hc;
            hj = hn;
            // publish FIRST (critical path for every other worker):
            // sc0 to our XCD L2, then the AGENT mirror (fire-and-forget)
            unsigned long long pk =
                ((unsigned long long)(unsigned)(s + 1) << 32) | (unsigned)__float_as_uint(hn);
            unsigned long long* d1 = hbuf  + ((size_t)((s + 1) & 1) << 9) + j;
            unsigned long long* d2 = hbuf2 + ((size_t)((s + 1) & 1) << 9) + j;
            asm volatile("global_store_dwordx2 %0, %1, off sc0"
                         :: "v"(d1), "v"(pk) : "memory");
            __hip_atomic_store(d2, pk, __ATOMIC_RELAXED, __HIP_MEMORY_SCOPE_AGENT);
            seq[(size_t)s * HHH + j] = hn;
            if (s == T_STEPS - 1) hT[j] = hn;
        }
        xz = nxz; xr = nxr; xh = nxh;
        // no trailing barrier: LDS double-buffered; next iter syncs after stage
    }
}

// ---------------------------------------------------------------- heads
__global__ __launch_bounds__(64) void heads_kernel(
    const float* __restrict__ seq, const float* __restrict__ Wp,
    const float* __restrict__ bp, const float* __restrict__ Wv,
    const float* __restrict__ bv, float* __restrict__ pol,
    float* __restrict__ val)
{
    const int s = blockIdx.x;
    const int l = threadIdx.x;
    const float* h = seq + (size_t)s * HHH;

    float acc[19];
#pragma unroll
    for (int jj = 0; jj < 19; ++jj) acc[jj] = 0.f;

#pragma unroll
    for (int kk = 0; kk < 8; ++kk) {
        const int k = kk * 64 + l;
        const float hv = h[k];
        const float* wrow = Wp + (size_t)k * AACT;
#pragma unroll
        for (int jj = 0; jj < AACT; ++jj) acc[jj] = fmaf(hv, wrow[jj], acc[jj]);
        acc[18] = fmaf(hv, Wv[k], acc[18]);
    }
#pragma unroll
    for (int jj = 0; jj < 19; ++jj) {
        float v = acc[jj];
#pragma unroll
        for (int off = 32; off; off >>= 1) v += __shfl_down(v, off, 64);
        acc[jj] = v;
    }
    if (l == 0) {
        float lg[18], mx = -1e30f;
#pragma unroll
        for (int jj = 0; jj < AACT; ++jj) { lg[jj] = acc[jj] + bp[jj]; mx = fmaxf(mx, lg[jj]); }
        float sum = 0.f;
#pragma unroll
        for (int jj = 0; jj < AACT; ++jj) { lg[jj] = __expf(lg[jj] - mx); sum += lg[jj]; }
        const float inv = 1.f / sum;
#pragma unroll
        for (int jj = 0; jj < AACT; ++jj) pol[(size_t)s * AACT + jj] = lg[jj] * inv;
        val[s] = acc[18] + bv[0];
    }
}

// ---------------------------------------------------------------- launch
extern "C" void kernel_launch(void* const* d_in, const int* in_sizes, int n_in,
                              void* d_out, int out_size, void* d_ws, size_t ws_size,
                              hipStream_t stream)
{
    const float* x  = (const float*)d_in[0];
    const float* h0 = (const float*)d_in[1];
    const float* W1 = (const float*)d_in[2];
    const float* b1 = (const float*)d_in[3];
    const float* W2 = (const float*)d_in[4];
    const float* b2 = (const float*)d_in[5];
    const float* Wg = (const float*)d_in[6];
    const float* Ug = (const float*)d_in[7];
    const float* bg = (const float*)d_in[8];
    const float* Wp = (const float*)d_in[9];
    const float* bp = (const float*)d_in[10];
    const float* Wv = (const float*)d_in[11];
    const float* bv = (const float*)d_in[12];

    char* ws = (char*)d_ws;
    __hip_bfloat16* W1b = (__hip_bfloat16*)(ws + 0);         // 2,097,152
    __hip_bfloat16* W2b = (__hip_bfloat16*)(ws + 2097152);   //   524,288
    __hip_bfloat16* Wgb = (__hip_bfloat16*)(ws + 2621440);   // 1,572,864
    __hip_bfloat16* z1b = (__hip_bfloat16*)(ws + 4194304);   // 8,388,608
    __hip_bfloat16* z2b = (__hip_bfloat16*)(ws + 12582912);  // 8,388,608
    float*          Xb  = (float*)(ws + 20971520);           // 50,331,648
    float*          seq = (float*)(ws + 71303168);           // 16,777,216
    unsigned long long* hbuf = (unsigned long long*)(ws + 88080384); // 8,192
    // hbuf needs NO init: step tags are self-validating vs 0xAA poison.
    // ctl and hbuf2 carved from z1b/z2b (both dead once gemm3 has read z2b;
    // init_ctl is stream-ordered after the gemms, before scan) — zero extra
    // ws footprint vs baseline.
    int* ctl = (int*)(ws + 4194304);
    unsigned long long* hbuf2 = (unsigned long long*)(ws + 12582912);

    float* out = (float*)d_out;
    float* pol = out;
    float* val = out + (size_t)T_STEPS * AACT;
    float* hT  = out + (size_t)T_STEPS * AACT + T_STEPS;

    cast_f32_bf16<<<DIN * DD / 256, 256, 0, stream>>>(W1, W1b, DIN * DD);
    cast_f32_bf16<<<DD * DD / 256, 256, 0, stream>>>(W2, W2b, DD * DD);
    cast_f32_bf16<<<DD * H3 / 256, 256, 0, stream>>>(Wg, Wgb, DD * H3);

    dim3 blk(256);
    gemm_bf16<<<dim3(T_STEPS / 64, DD / 64), blk, 0, stream>>>(
        x, nullptr, W1b, b1, z1b, nullptr, T_STEPS, DD, DIN, 1);
    gemm_bf16<<<dim3(T_STEPS / 64, DD / 64), blk, 0, stream>>>(
        nullptr, z1b, W2b, b2, z2b, nullptr, T_STEPS, DD, DD, 1);
    gemm_bf16<<<dim3(T_STEPS / 64, H3 / 64), blk, 0, stream>>>(
        nullptr, z2b, Wgb, bg, nullptr, Xb, T_STEPS, H3, DD, 0);

    init_ctl<<<1, 1, 0, stream>>>(ctl);
    scan_kernel<<<SCAN_GRID, 256, 0, stream>>>(Xb, Ug, bg, h0, seq, hbuf, hbuf2, hT, ctl);

    heads_kernel<<<T_STEPS, 64, 0, stream>>>(seq, Wp, bp, Wv, bv, pol, val);
}

// Round 4
// 12982.582 us; speedup vs baseline: 21.3804x; 21.3804x over previous
//
#include <hip/hip_runtime.h>
#include <hip/hip_bf16.h>

// Problem: T=8192 steps, D_IN=2048, D=512 dense, H=512 cell, A=18 actions.
// out = concat(policy [T,18], value [T,1], hT [1,512]) fp32, 156160 elems.
//
// R3: R2's only bug was DPP direction. row_shr:N moves data to HIGHER lanes
// (canonical wave-reduce reads lane 63), so the 16-group sum landed in lane
// 15 while lane 0 (kp==0, the consumer) kept only its own partial -> value
// head absmax 0.177. Fix: row_shl:{8,4,2,1} (lane i reads lane i+N,
// bound_ctrl 0-fills out-of-row) accumulates the sum into lane 0 — exact
// dual of baseline __shfl_down(...,off,16). Everything else identical to R2:
// packed 16B tagged slots (1 poll load/thread, 256 publish stores/step),
// device-scope sc0 sc1 protocol (proven), DPP VALU-only reduce, paired
// float2 seq stores, AGPR-pinned weights, X-prefetch-under-spin.

#define T_STEPS 8192
#define DIN 2048
#define DD 512
#define HHH 512
#define AACT 18
#define H3 1536
#define NWG 32          // worker WGs; each owns 16 rows of h

typedef __attribute__((ext_vector_type(8))) short short8;
typedef __attribute__((ext_vector_type(4))) float f32x4;
typedef __attribute__((ext_vector_type(4))) int i32x4;

// ---------------------------------------------------------------- casts
__global__ void cast_f32_bf16(const float* __restrict__ in,
                              __hip_bfloat16* __restrict__ out, int n)
{
    int i = blockIdx.x * 256 + threadIdx.x;
    if (i < n) out[i] = __float2bfloat16(in[i]);
}

// ctl[2] = global abort flag (dead-man). ctl[0..1] unused this round.
__global__ void init_ctl(int* ctl) { ctl[0] = 0; ctl[1] = 0; ctl[2] = 0; }

// ---------------------------------------------------------------- GEMM
// C[M,N] = act(A[M,K] @ B[K,N] + bias). A either fp32 (cast on stage) or bf16.
// Block 256 (4 waves), tile 64x64, K-tile 32.
// MFMA 16x16x32 bf16: D: col=lane&15, row=quad*4+reg (verified m89/m91).
__global__ __launch_bounds__(256) void gemm_bf16(
    const float* __restrict__ A32, const __hip_bfloat16* __restrict__ A16,
    const __hip_bfloat16* __restrict__ B, const float* __restrict__ bias,
    __hip_bfloat16* __restrict__ Cb, float* __restrict__ Cf,
    int M, int N, int K, int relu)
{
    const int m0 = blockIdx.x * 64;
    const int n0 = blockIdx.y * 64;
    const int t  = threadIdx.x;
    const int wave = t >> 6;
    const int lane = t & 63;
    const int quad = lane >> 4;
    const int l16  = lane & 15;

    __shared__ __align__(16) __hip_bfloat16 As[64 * 40];
    __shared__ __align__(16) __hip_bfloat16 Bs[64 * 40];

    f32x4 acc[4];
#pragma unroll
    for (int c = 0; c < 4; ++c) acc[c] = (f32x4){0.f, 0.f, 0.f, 0.f};

    const int ar = t >> 2, akc = (t & 3) * 8;
    const int bk = t >> 3, bn  = (t & 7) * 8;

    for (int kb = 0; kb < K; kb += 32) {
        if (A32) {
            const float* src = A32 + (size_t)(m0 + ar) * K + kb + akc;
            float4 f0 = *(const float4*)(src);
            float4 f1 = *(const float4*)(src + 4);
            union { short8 v; __hip_bfloat16 h[8]; } u;
            u.h[0] = __float2bfloat16(f0.x); u.h[1] = __float2bfloat16(f0.y);
            u.h[2] = __float2bfloat16(f0.z); u.h[3] = __float2bfloat16(f0.w);
            u.h[4] = __float2bfloat16(f1.x); u.h[5] = __float2bfloat16(f1.y);
            u.h[6] = __float2bfloat16(f1.z); u.h[7] = __float2bfloat16(f1.w);
            *(short8*)&As[ar * 40 + akc] = u.v;
        } else {
            const __hip_bfloat16* src = A16 + (size_t)(m0 + ar) * K + kb + akc;
            *(short8*)&As[ar * 40 + akc] = *(const short8*)src;
        }
        {
            const __hip_bfloat16* src = B + (size_t)(kb + bk) * N + n0 + bn;
            short8 v = *(const short8*)src;
            const __hip_bfloat16* vh = (const __hip_bfloat16*)&v;
#pragma unroll
            for (int i = 0; i < 8; ++i) Bs[(bn + i) * 40 + bk] = vh[i];
        }
        __syncthreads();

        short8 a = *(const short8*)&As[(wave * 16 + l16) * 40 + quad * 8];
#pragma unroll
        for (int c = 0; c < 4; ++c) {
            short8 b = *(const short8*)&Bs[(c * 16 + l16) * 40 + quad * 8];
            acc[c] = __builtin_amdgcn_mfma_f32_16x16x32_bf16(a, b, acc[c], 0, 0, 0);
        }
        __syncthreads();
    }

#pragma unroll
    for (int c = 0; c < 4; ++c) {
        const int col = n0 + c * 16 + l16;
        const float bb = bias ? bias[col] : 0.f;
#pragma unroll
        for (int r = 0; r < 4; ++r) {
            const int row = m0 + wave * 16 + quad * 4 + r;
            float v = acc[c][r] + bb;
            if (relu) v = fmaxf(v, 0.f);
            if (Cb) Cb[(size_t)row * N + col] = __float2bfloat16(v);
            if (Cf) Cf[(size_t)row * N + col] = v;
        }
    }
}

// --------------------------------------------------------------- DPP reduce
// Reduce-to-lane0 within each 16-lane row via row_shl:N — lane i reads lane
// i+N; reads past the row end are 0-filled (bound_ctrl=true). This is the
// dual of the canonical row_shr tree (whose sum lands in the TOP lane) and
// matches baseline __shfl_down(x, off, 16) semantics.
template <int CTRL>
__device__ __forceinline__ float dpp_red_add(float x)
{
    int sh = __builtin_amdgcn_update_dpp(0, __float_as_int(x), CTRL, 0xF, 0xF, true);
    return x + __int_as_float(sh);
}

// ---------------------------------------------------------------- GRU scan
// 32 persistent WGs x 256 threads (waves_per_eu(1,1) => each WG alone on its
// CU). WG i owns h rows [16i, 16i+16).
// Thread t: jl=t>>4 (row), kp=t&15 (k-chunk [32kp,32kp+32)).
// h exchange (device scope, PROVEN): packed 16B slots, double-buffered by
// step parity. Slot p holds {h[2p], tag, h[2p+1], tag}; each 8B half is
// self-validating (torn writes detected, never consumed). sc0+sc1 bypasses
// L1 and L2 definitively (>= agent scope). 0xAA poison never matches a tag.
// Thread t polls exactly slot t of the active parity: 8192 poll loads and
// 256 publish stores per step device-wide (halved vs baseline).
__global__ __launch_bounds__(256)
__attribute__((amdgpu_waves_per_eu(1, 1)))
void scan_kernel(
    const float* __restrict__ X,            // [T][1536] = z@Wg + bg[0]
    const float* __restrict__ Ug,           // [512][1536]
    const float* __restrict__ bg,           // [2][1536]; row 1 = recurrent bias
    const float* __restrict__ h0,           // [512] prev_hidden
    float* __restrict__ seq,                // [T][512]
    i32x4* __restrict__ hbuf,               // [2][256] packed tagged h pairs
    float* __restrict__ hT,                 // [512] -> d_out tail
    int* __restrict__ ctl)                  // ctl[2] = abort flag
{
    const int t  = threadIdx.x;
    const int wg = blockIdx.x;
    const int jl = t >> 4;
    const int kp = t & 15;
    const int j  = wg * 16 + jl;
    const int k0 = kp * 32;

    // double-buffered h stage; row stride 36 words = 144B (16B aligned;
    // b128 reads across 16 kp-lanes alias banks 2-way = free per m136)
    __shared__ __align__(16) float h_lds[2][16 * 36];
    __shared__ int wg_abort;
    if (t == 0) wg_abort = 0;

    float wz[32], wr[32], wh[32];
#pragma unroll
    for (int m = 0; m < 32; ++m) {
        const float* row = Ug + (size_t)(k0 + m) * H3;
        wz[m] = row[j];
        wr[m] = row[512 + j];
        wh[m] = row[1024 + j];
    }
    // pin all 96 weights into AGPRs: guaranteed register residency for the
    // whole step loop (no scratch spill path exists for "a"-pinned values)
#pragma unroll
    for (int m = 0; m < 32; ++m) {
        asm volatile("" : "+a"(wz[m]), "+a"(wr[m]), "+a"(wh[m]));
    }

    const float* brec = bg + H3;
    const float bz = brec[j], brr = brec[512 + j], bh = brec[1024 + j];
    float hj = h0[j];  // my h element (kp==0 lanes)

    // staging: thread t owns slot t = values h[2t], h[2t+1]
    // LDS address of h[2t] = (2t>>5)*36 + (2t&31) = jl*36 + 2*kp
    const int a_e = jl * 36 + 2 * kp;

    // prefetch X[0]
    float xz = 0.f, xr = 0.f, xh = 0.f;
    if (kp == 0) { xz = X[j]; xr = X[512 + j]; xh = X[1024 + j]; }

    for (int s = 0; s < T_STEPS; ++s) {
        float* hl = h_lds[s & 1];

        // ---- prefetch X[s+1] FIRST: retires under the spin
        float nxz = 0.f, nxr = 0.f, nxh = 0.f;
        if (kp == 0 && s + 1 < T_STEPS) {
            const float* Xs = X + (size_t)(s + 1) * H3;
            nxz = Xs[j]; nxr = Xs[512 + j]; nxh = Xs[1024 + j];
        }

        // ---- acquire h_s (one 16B tagged slot per thread)
        if (s == 0) {
            *(float2*)&hl[a_e] = make_float2(h0[2 * t], h0[2 * t + 1]);
        } else {
            const i32x4* sp = hbuf + ((s & 1) << 8) + t;
            i32x4 d;
            int guard = 0;
            for (;;) {
                // load+wait in ONE asm block: check provably uses completed data
                asm volatile("global_load_dwordx4 %0, %1, off sc0 sc1\n\t"
                             "s_waitcnt vmcnt(0)"
                             : "=v"(d) : "v"(sp) : "memory");
                if (__builtin_expect(d[1] == s && d[3] == s, 1)) break;
                if ((++guard & 255) == 0) {   // dead-man / global abort
                    int ab = __hip_atomic_load(ctl + 2, __ATOMIC_RELAXED,
                                               __HIP_MEMORY_SCOPE_AGENT);
                    if (ab || guard > (1 << 14)) {
                        wg_abort = 1;
                        __hip_atomic_store(ctl + 2, 1, __ATOMIC_RELAXED,
                                           __HIP_MEMORY_SCOPE_AGENT);
                        break;
                    }
                }
            }
            *(float2*)&hl[a_e] =
                make_float2(__int_as_float(d[0]), __int_as_float(d[2]));
        }
        __syncthreads();
        if (wg_abort) return;   // uniform exit: no barrier divergence

        // ---- partial matvec: 32 k-values x 3 gate columns
        float accz = 0.f, accr = 0.f, acch = 0.f;
        const float* hb = &hl[kp * 36];
#pragma unroll
        for (int m = 0; m < 32; m += 4) {
            float4 hv = *(const float4*)(hb + m);
            accz = fmaf(hv.x, wz[m    ], accz);
            accz = fmaf(hv.y, wz[m + 1], accz);
            accz = fmaf(hv.z, wz[m + 2], accz);
            accz = fmaf(hv.w, wz[m + 3], accz);
            accr = fmaf(hv.x, wr[m    ], accr);
            accr = fmaf(hv.y, wr[m + 1], accr);
            accr = fmaf(hv.z, wr[m + 2], accr);
            accr = fmaf(hv.w, wr[m + 3], accr);
            acch = fmaf(hv.x, wh[m    ], acch);
            acch = fmaf(hv.y, wh[m + 1], acch);
            acch = fmaf(hv.z, wh[m + 2], acch);
            acch = fmaf(hv.w, wh[m + 3], acch);
        }
        // reduce across the 16 kp lanes: VALU-only DPP row_shl tree,
        // sum accumulates INTO lane 0 of each 16-lane row (= kp==0)
        accz = dpp_red_add<0x108>(accz);  // += lane+8
        accr = dpp_red_add<0x108>(accr);
        acch = dpp_red_add<0x108>(acch);
        accz = dpp_red_add<0x104>(accz);  // += lane+4
        accr = dpp_red_add<0x104>(accr);
        acch = dpp_red_add<0x104>(acch);
        accz = dpp_red_add<0x102>(accz);  // += lane+2
        accr = dpp_red_add<0x102>(accr);
        acch = dpp_red_add<0x102>(acch);
        accz = dpp_red_add<0x101>(accz);  // += lane+1
        accr = dpp_red_add<0x101>(accr);
        acch = dpp_red_add<0x101>(acch);

        if (kp == 0) {
            const float rz = accz + bz, rr = accr + brr, rh = acch + bh;
            const float zt = 1.f / (1.f + __expf(-(xz + rz)));
            const float rt = 1.f / (1.f + __expf(-(xr + rr)));
            const float hc = 1.f / (1.f + __expf(-(xh + rt * rh)));
            const float hn = zt * hj + (1.f - zt) * hc;
            hj = hn;
            // pair with odd-j mate (active lanes here are 0,16,32,48)
            const float ho = __shfl_down(hn, 16, 64);
            if ((t & 31) == 0) {
                i32x4 pk;
                pk[0] = __float_as_int(hn); pk[1] = s + 1;
                pk[2] = __float_as_int(ho); pk[3] = s + 1;
                i32x4* dst = hbuf + (((s + 1) & 1) << 8) + (wg * 8 + (jl >> 1));
                // publish FIRST: this store is the device-wide critical path
                asm volatile("global_store_dwordx4 %0, %1, off sc0 sc1"
                             :: "v"(dst), "v"(pk) : "memory");
                *(float2*)&seq[(size_t)s * HHH + j] = make_float2(hn, ho);
            }
            if (s == T_STEPS - 1) hT[j] = hn;
        }
        xz = nxz; xr = nxr; xh = nxh;
        // no trailing barrier: LDS double-buffered; next iter syncs after stage
    }
}

// ---------------------------------------------------------------- heads
__global__ __launch_bounds__(64) void heads_kernel(
    const float* __restrict__ seq, const float* __restrict__ Wp,
    const float* __restrict__ bp, const float* __restrict__ Wv,
    const float* __restrict__ bv, float* __restrict__ pol,
    float* __restrict__ val)
{
    const int s = blockIdx.x;
    const int l = threadIdx.x;
    const float* h = seq + (size_t)s * HHH;

    float acc[19];
#pragma unroll
    for (int jj = 0; jj < 19; ++jj) acc[jj] = 0.f;

#pragma unroll
    for (int kk = 0; kk < 8; ++kk) {
        const int k = kk * 64 + l;
        const float hv = h[k];
        const float* wrow = Wp + (size_t)k * AACT;
#pragma unroll
        for (int jj = 0; jj < AACT; ++jj) acc[jj] = fmaf(hv, wrow[jj], acc[jj]);
        acc[18] = fmaf(hv, Wv[k], acc[18]);
    }
#pragma unroll
    for (int jj = 0; jj < 19; ++jj) {
        float v = acc[jj];
#pragma unroll
        for (int off = 32; off; off >>= 1) v += __shfl_down(v, off, 64);
        acc[jj] = v;
    }
    if (l == 0) {
        float lg[18], mx = -1e30f;
#pragma unroll
        for (int jj = 0; jj < AACT; ++jj) { lg[jj] = acc[jj] + bp[jj]; mx = fmaxf(mx, lg[jj]); }
        float sum = 0.f;
#pragma unroll
        for (int jj = 0; jj < AACT; ++jj) { lg[jj] = __expf(lg[jj] - mx); sum += lg[jj]; }
        const float inv = 1.f / sum;
#pragma unroll
        for (int jj = 0; jj < AACT; ++jj) pol[(size_t)s * AACT + jj] = lg[jj] * inv;
        val[s] = acc[18] + bv[0];
    }
}

// ---------------------------------------------------------------- launch
extern "C" void kernel_launch(void* const* d_in, const int* in_sizes, int n_in,
                              void* d_out, int out_size, void* d_ws, size_t ws_size,
                              hipStream_t stream)
{
    const float* x  = (const float*)d_in[0];
    const float* h0 = (const float*)d_in[1];
    const float* W1 = (const float*)d_in[2];
    const float* b1 = (const float*)d_in[3];
    const float* W2 = (const float*)d_in[4];
    const float* b2 = (const float*)d_in[5];
    const float* Wg = (const float*)d_in[6];
    const float* Ug = (const float*)d_in[7];
    const float* bg = (const float*)d_in[8];
    const float* Wp = (const float*)d_in[9];
    const float* bp = (const float*)d_in[10];
    const float* Wv = (const float*)d_in[11];
    const float* bv = (const float*)d_in[12];

    char* ws = (char*)d_ws;
    __hip_bfloat16* W1b = (__hip_bfloat16*)(ws + 0);         // 2,097,152
    __hip_bfloat16* W2b = (__hip_bfloat16*)(ws + 2097152);   //   524,288
    __hip_bfloat16* Wgb = (__hip_bfloat16*)(ws + 2621440);   // 1,572,864
    __hip_bfloat16* z1b = (__hip_bfloat16*)(ws + 4194304);   // 8,388,608
    __hip_bfloat16* z2b = (__hip_bfloat16*)(ws + 12582912);  // 8,388,608
    float*          Xb  = (float*)(ws + 20971520);           // 50,331,648
    float*          seq = (float*)(ws + 71303168);           // 16,777,216
    i32x4*          hbuf = (i32x4*)(ws + 88080384);          // 2*256*16B = 8,192
    // hbuf needs NO init: step tags are self-validating vs 0xAA poison.
    // ctl carved from z1b (dead after gemm2 reads it; init_ctl is
    // stream-ordered after the gemms, before scan) — zero extra ws footprint.
    int* ctl = (int*)(ws + 4194304);

    float* out = (float*)d_out;
    float* pol = out;
    float* val = out + (size_t)T_STEPS * AACT;
    float* hT  = out + (size_t)T_STEPS * AACT + T_STEPS;

    cast_f32_bf16<<<DIN * DD / 256, 256, 0, stream>>>(W1, W1b, DIN * DD);
    cast_f32_bf16<<<DD * DD / 256, 256, 0, stream>>>(W2, W2b, DD * DD);
    cast_f32_bf16<<<DD * H3 / 256, 256, 0, stream>>>(Wg, Wgb, DD * H3);

    dim3 blk(256);
    gemm_bf16<<<dim3(T_STEPS / 64, DD / 64), blk, 0, stream>>>(
        x, nullptr, W1b, b1, z1b, nullptr, T_STEPS, DD, DIN, 1);
    gemm_bf16<<<dim3(T_STEPS / 64, DD / 64), blk, 0, stream>>>(
        nullptr, z1b, W2b, b2, z2b, nullptr, T_STEPS, DD, DD, 1);
    gemm_bf16<<<dim3(T_STEPS / 64, H3 / 64), blk, 0, stream>>>(
        nullptr, z2b, Wgb, bg, nullptr, Xb, T_STEPS, H3, DD, 0);

    init_ctl<<<1, 1, 0, stream>>>(ctl);
    scan_kernel<<<NWG, 256, 0, stream>>>(Xb, Ug, bg, h0, seq, hbuf, hT, ctl);

    heads_kernel<<<T_STEPS, 64, 0, stream>>>(seq, Wp, bp, Wv, bv, pol, val);
}

// Round 5
// 12397.823 us; speedup vs baseline: 22.3888x; 1.0472x over previous
//
#include <hip/hip_runtime.h>
#include <hip/hip_bf16.h>

// Problem: T=8192 steps, D_IN=2048, D=512 dense, H=512 cell, A=18 actions.
// out = concat(policy [T,18], value [T,1], hT [1,512]) fp32, 156160 elems.
//
// R4: R3 (= R2 structure, DPP fixed) was a WASH vs baseline -> scan is not
// instruction-bound. Found self-inflicted serialization: R2/R3's inline-asm
// poll ends with s_waitcnt vmcnt(0), which also drains the X[s+1] prefetch
// (3 HBM loads) sharing the wave's vmcnt -> publisher lanes' first poll of
// every step stalls ~600-900cyc, delaying every publish. Baseline's
// __hip_atomic_load spin gets compiler-exact vmcnt(3) (X loads stay in
// flight). This round: revert sync to the baseline compiler-tracked form
// (8B tagged slots, immediate publish, exact-counted polls), KEEP the
// proven DPP row_shl reduce (replaces 12 serial ds_bpermute, ~300cyc).

#define T_STEPS 8192
#define DIN 2048
#define DD 512
#define HHH 512
#define AACT 18
#define H3 1536
#define NWG 32          // worker WGs; each owns 16 rows of h

typedef __attribute__((ext_vector_type(8))) short short8;
typedef __attribute__((ext_vector_type(4))) float f32x4;

// ---------------------------------------------------------------- casts
__global__ void cast_f32_bf16(const float* __restrict__ in,
                              __hip_bfloat16* __restrict__ out, int n)
{
    int i = blockIdx.x * 256 + threadIdx.x;
    if (i < n) out[i] = __float2bfloat16(in[i]);
}

// ctl[2] = global abort flag (dead-man). ctl[0..1] unused.
__global__ void init_ctl(int* ctl) { ctl[0] = 0; ctl[1] = 0; ctl[2] = 0; }

// ---------------------------------------------------------------- GEMM
// C[M,N] = act(A[M,K] @ B[K,N] + bias). A either fp32 (cast on stage) or bf16.
// Block 256 (4 waves), tile 64x64, K-tile 32.
// MFMA 16x16x32 bf16: D: col=lane&15, row=quad*4+reg (verified m89/m91).
__global__ __launch_bounds__(256) void gemm_bf16(
    const float* __restrict__ A32, const __hip_bfloat16* __restrict__ A16,
    const __hip_bfloat16* __restrict__ B, const float* __restrict__ bias,
    __hip_bfloat16* __restrict__ Cb, float* __restrict__ Cf,
    int M, int N, int K, int relu)
{
    const int m0 = blockIdx.x * 64;
    const int n0 = blockIdx.y * 64;
    const int t  = threadIdx.x;
    const int wave = t >> 6;
    const int lane = t & 63;
    const int quad = lane >> 4;
    const int l16  = lane & 15;

    __shared__ __align__(16) __hip_bfloat16 As[64 * 40];
    __shared__ __align__(16) __hip_bfloat16 Bs[64 * 40];

    f32x4 acc[4];
#pragma unroll
    for (int c = 0; c < 4; ++c) acc[c] = (f32x4){0.f, 0.f, 0.f, 0.f};

    const int ar = t >> 2, akc = (t & 3) * 8;
    const int bk = t >> 3, bn  = (t & 7) * 8;

    for (int kb = 0; kb < K; kb += 32) {
        if (A32) {
            const float* src = A32 + (size_t)(m0 + ar) * K + kb + akc;
            float4 f0 = *(const float4*)(src);
            float4 f1 = *(const float4*)(src + 4);
            union { short8 v; __hip_bfloat16 h[8]; } u;
            u.h[0] = __float2bfloat16(f0.x); u.h[1] = __float2bfloat16(f0.y);
            u.h[2] = __float2bfloat16(f0.z); u.h[3] = __float2bfloat16(f0.w);
            u.h[4] = __float2bfloat16(f1.x); u.h[5] = __float2bfloat16(f1.y);
            u.h[6] = __float2bfloat16(f1.z); u.h[7] = __float2bfloat16(f1.w);
            *(short8*)&As[ar * 40 + akc] = u.v;
        } else {
            const __hip_bfloat16* src = A16 + (size_t)(m0 + ar) * K + kb + akc;
            *(short8*)&As[ar * 40 + akc] = *(const short8*)src;
        }
        {
            const __hip_bfloat16* src = B + (size_t)(kb + bk) * N + n0 + bn;
            short8 v = *(const short8*)src;
            const __hip_bfloat16* vh = (const __hip_bfloat16*)&v;
#pragma unroll
            for (int i = 0; i < 8; ++i) Bs[(bn + i) * 40 + bk] = vh[i];
        }
        __syncthreads();

        short8 a = *(const short8*)&As[(wave * 16 + l16) * 40 + quad * 8];
#pragma unroll
        for (int c = 0; c < 4; ++c) {
            short8 b = *(const short8*)&Bs[(c * 16 + l16) * 40 + quad * 8];
            acc[c] = __builtin_amdgcn_mfma_f32_16x16x32_bf16(a, b, acc[c], 0, 0, 0);
        }
        __syncthreads();
    }

#pragma unroll
    for (int c = 0; c < 4; ++c) {
        const int col = n0 + c * 16 + l16;
        const float bb = bias ? bias[col] : 0.f;
#pragma unroll
        for (int r = 0; r < 4; ++r) {
            const int row = m0 + wave * 16 + quad * 4 + r;
            float v = acc[c][r] + bb;
            if (relu) v = fmaxf(v, 0.f);
            if (Cb) Cb[(size_t)row * N + col] = __float2bfloat16(v);
            if (Cf) Cf[(size_t)row * N + col] = v;
        }
    }
}

// --------------------------------------------------------------- DPP reduce
// Reduce-to-lane0 within each 16-lane row via row_shl:N — lane i reads lane
// i+N; reads past the row end are 0-filled (bound_ctrl=true). Dual of the
// canonical row_shr tree; matches __shfl_down(x, off, 16). Verified R3
// (absmax 0.0039).
template <int CTRL>
__device__ __forceinline__ float dpp_red_add(float x)
{
    int sh = __builtin_amdgcn_update_dpp(0, __float_as_int(x), CTRL, 0xF, 0xF, true);
    return x + __int_as_float(sh);
}

// ---------------------------------------------------------------- GRU scan
// 32 persistent WGs x 256 threads (waves_per_eu(1,1): WG alone on its CU).
// WG i owns h rows [16i, 16i+16). Thread t: jl=t>>4 (row), kp=t&15
// (k-chunk [32kp, 32kp+32)).
// h exchange (device scope, PROVEN baseline protocol): 8B tagged slots
// {f32 val, u32 step}, double-buffered by step parity, RELAXED AGENT
// atomics. Compiler-exact vmcnt counting keeps the X[s+1] prefetch loads
// in flight through the spin (the R2/R3 asm spin's vmcnt(0) drained them
// on the publishers' critical path — reverted). Publish is immediate
// per-j 8B (no pairing shfl before the store).
__global__ __launch_bounds__(256)
__attribute__((amdgpu_waves_per_eu(1, 1)))
void scan_kernel(
    const float* __restrict__ X,            // [T][1536] = z@Wg + bg[0]
    const float* __restrict__ Ug,           // [512][1536]
    const float* __restrict__ bg,           // [2][1536]; row 1 = recurrent bias
    const float* __restrict__ h0,           // [512] prev_hidden
    float* __restrict__ seq,                // [T][512]
    unsigned long long* __restrict__ hbuf,  // [2][512] tagged h (no init needed)
    float* __restrict__ hT,                 // [512] -> d_out tail
    int* __restrict__ ctl)                  // ctl[2] = abort flag
{
    const int t  = threadIdx.x;
    const int wg = blockIdx.x;
    const int jl = t >> 4;
    const int kp = t & 15;
    const int j  = wg * 16 + jl;
    const int k0 = kp * 32;

    // double-buffered h stage; row stride 36 words = 144B (16B aligned;
    // b128 reads across 16 kp-lanes alias banks 2-way = free per m136)
    __shared__ __align__(16) float h_lds[2][16 * 36];
    __shared__ int wg_abort;
    if (t == 0) wg_abort = 0;

    float wz[32], wr[32], wh[32];
#pragma unroll
    for (int m = 0; m < 32; ++m) {
        const float* row = Ug + (size_t)(k0 + m) * H3;
        wz[m] = row[j];
        wr[m] = row[512 + j];
        wh[m] = row[1024 + j];
    }
    // pin all 96 weights into AGPRs: guaranteed register residency for the
    // whole step loop (no scratch spill path exists for "a"-pinned values)
#pragma unroll
    for (int m = 0; m < 32; ++m) {
        asm volatile("" : "+a"(wz[m]), "+a"(wr[m]), "+a"(wh[m]));
    }

    const float* brec = bg + H3;
    const float bz = brec[j], brr = brec[512 + j], bh = brec[1024 + j];
    float hj = h0[j];  // my h element (kp==0 lanes)

    // staging slots for this thread (baseline layout: thread t owns k1,k2)
    const int k1 = t, k2 = t + 256;
    const int a1 = (k1 >> 5) * 36 + (k1 & 31);
    const int a2 = (k2 >> 5) * 36 + (k2 & 31);

    // prefetch X[0]
    float xz = 0.f, xr = 0.f, xh = 0.f;
    if (kp == 0) { xz = X[j]; xr = X[512 + j]; xh = X[1024 + j]; }

    for (int s = 0; s < T_STEPS; ++s) {
        float* hl = h_lds[s & 1];

        // ---- prefetch X[s+1] FIRST: retires under the spin (exact vmcnt
        // counting leaves these in flight through the poll waits)
        float nxz = 0.f, nxr = 0.f, nxh = 0.f;
        if (kp == 0 && s + 1 < T_STEPS) {
            const float* Xs = X + (size_t)(s + 1) * H3;
            nxz = Xs[j]; nxr = Xs[512 + j]; nxh = Xs[1024 + j];
        }

        // ---- acquire h_s (spin on tagged slots, both polls in flight)
        if (s == 0) {
            hl[a1] = h0[k1];
            hl[a2] = h0[k2];
        } else {
            const unsigned long long* src = hbuf + ((size_t)(s & 1) << 9);
            unsigned long long v1 = __hip_atomic_load(src + k1, __ATOMIC_RELAXED, __HIP_MEMORY_SCOPE_AGENT);
            unsigned long long v2 = __hip_atomic_load(src + k2, __ATOMIC_RELAXED, __HIP_MEMORY_SCOPE_AGENT);
            bool ok1 = (unsigned)(v1 >> 32) == (unsigned)s;
            bool ok2 = (unsigned)(v2 >> 32) == (unsigned)s;
            int guard = 0;
            while (!(ok1 && ok2)) {
                if (!ok1) v1 = __hip_atomic_load(src + k1, __ATOMIC_RELAXED, __HIP_MEMORY_SCOPE_AGENT);
                if (!ok2) v2 = __hip_atomic_load(src + k2, __ATOMIC_RELAXED, __HIP_MEMORY_SCOPE_AGENT);
                ok1 = (unsigned)(v1 >> 32) == (unsigned)s;
                ok2 = (unsigned)(v2 >> 32) == (unsigned)s;
                if ((++guard & 1023) == 0) {   // dead-man / global abort
                    int ab = __hip_atomic_load(ctl + 2, __ATOMIC_RELAXED,
                                               __HIP_MEMORY_SCOPE_AGENT);
                    if (ab || guard > (1 << 16)) {
                        wg_abort = 1;
                        __hip_atomic_store(ctl + 2, 1, __ATOMIC_RELAXED,
                                           __HIP_MEMORY_SCOPE_AGENT);
                        break;
                    }
                }
            }
            hl[a1] = __uint_as_float((unsigned)v1);
            hl[a2] = __uint_as_float((unsigned)v2);
        }
        __syncthreads();
        if (wg_abort) return;   // uniform exit: no barrier divergence

        // ---- partial matvec: 32 k-values x 3 gate columns
        float accz = 0.f, accr = 0.f, acch = 0.f;
        const float* hb = &hl[kp * 36];
#pragma unroll
        for (int m = 0; m < 32; m += 4) {
            float4 hv = *(const float4*)(hb + m);
            accz = fmaf(hv.x, wz[m    ], accz);
            accz = fmaf(hv.y, wz[m + 1], accz);
            accz = fmaf(hv.z, wz[m + 2], accz);
            accz = fmaf(hv.w, wz[m + 3], accz);
            accr = fmaf(hv.x, wr[m    ], accr);
            accr = fmaf(hv.y, wr[m + 1], accr);
            accr = fmaf(hv.z, wr[m + 2], accr);
            accr = fmaf(hv.w, wr[m + 3], accr);
            acch = fmaf(hv.x, wh[m    ], acch);
            acch = fmaf(hv.y, wh[m + 1], acch);
            acch = fmaf(hv.z, wh[m + 2], acch);
            acch = fmaf(hv.w, wh[m + 3], acch);
        }
        // reduce across the 16 kp lanes: VALU-only DPP row_shl tree,
        // sum accumulates INTO lane 0 of each 16-lane row (= kp==0)
        accz = dpp_red_add<0x108>(accz);  // += lane+8
        accr = dpp_red_add<0x108>(accr);
        acch = dpp_red_add<0x108>(acch);
        accz = dpp_red_add<0x104>(accz);  // += lane+4
        accr = dpp_red_add<0x104>(accr);
        acch = dpp_red_add<0x104>(acch);
        accz = dpp_red_add<0x102>(accz);  // += lane+2
        accr = dpp_red_add<0x102>(accr);
        acch = dpp_red_add<0x102>(acch);
        accz = dpp_red_add<0x101>(accz);  // += lane+1
        accr = dpp_red_add<0x101>(accr);
        acch = dpp_red_add<0x101>(acch);

        if (kp == 0) {
            const float rz = accz + bz, rr = accr + brr, rh = acch + bh;
            const float zt = 1.f / (1.f + __expf(-(xz + rz)));
            const float rt = 1.f / (1.f + __expf(-(xr + rr)));
            const float hc = 1.f / (1.f + __expf(-(xh + rt * rh)));
            const float hn = zt * hj + (1.f - zt) * hc;
            hj = hn;
            // publish FIRST and IMMEDIATELY: this store is the device-wide
            // critical path (no pairing shuffle before it)
            unsigned long long pk =
                ((unsigned long long)(unsigned)(s + 1) << 32) | (unsigned)__float_as_uint(hn);
            __hip_atomic_store(hbuf + (size_t)(((s + 1) & 1) << 9) + j, pk,
                               __ATOMIC_RELAXED, __HIP_MEMORY_SCOPE_AGENT);
            seq[(size_t)s * HHH + j] = hn;
            if (s == T_STEPS - 1) hT[j] = hn;
        }
        xz = nxz; xr = nxr; xh = nxh;
        // no trailing barrier: LDS double-buffered; next iter syncs after stage
    }
}

// ---------------------------------------------------------------- heads
__global__ __launch_bounds__(64) void heads_kernel(
    const float* __restrict__ seq, const float* __restrict__ Wp,
    const float* __restrict__ bp, const float* __restrict__ Wv,
    const float* __restrict__ bv, float* __restrict__ pol,
    float* __restrict__ val)
{
    const int s = blockIdx.x;
    const int l = threadIdx.x;
    const float* h = seq + (size_t)s * HHH;

    float acc[19];
#pragma unroll
    for (int jj = 0; jj < 19; ++jj) acc[jj] = 0.f;

#pragma unroll
    for (int kk = 0; kk < 8; ++kk) {
        const int k = kk * 64 + l;
        const float hv = h[k];
        const float* wrow = Wp + (size_t)k * AACT;
#pragma unroll
        for (int jj = 0; jj < AACT; ++jj) acc[jj] = fmaf(hv, wrow[jj], acc[jj]);
        acc[18] = fmaf(hv, Wv[k], acc[18]);
    }
#pragma unroll
    for (int jj = 0; jj < 19; ++jj) {
        float v = acc[jj];
#pragma unroll
        for (int off = 32; off; off >>= 1) v += __shfl_down(v, off, 64);
        acc[jj] = v;
    }
    if (l == 0) {
        float lg[18], mx = -1e30f;
#pragma unroll
        for (int jj = 0; jj < AACT; ++jj) { lg[jj] = acc[jj] + bp[jj]; mx = fmaxf(mx, lg[jj]); }
        float sum = 0.f;
#pragma unroll
        for (int jj = 0; jj < AACT; ++jj) { lg[jj] = __expf(lg[jj] - mx); sum += lg[jj]; }
        const float inv = 1.f / sum;
#pragma unroll
        for (int jj = 0; jj < AACT; ++jj) pol[(size_t)s * AACT + jj] = lg[jj] * inv;
        val[s] = acc[18] + bv[0];
    }
}

// ---------------------------------------------------------------- launch
extern "C" void kernel_launch(void* const* d_in, const int* in_sizes, int n_in,
                              void* d_out, int out_size, void* d_ws, size_t ws_size,
                              hipStream_t stream)
{
    const float* x  = (const float*)d_in[0];
    const float* h0 = (const float*)d_in[1];
    const float* W1 = (const float*)d_in[2];
    const float* b1 = (const float*)d_in[3];
    const float* W2 = (const float*)d_in[4];
    const float* b2 = (const float*)d_in[5];
    const float* Wg = (const float*)d_in[6];
    const float* Ug = (const float*)d_in[7];
    const float* bg = (const float*)d_in[8];
    const float* Wp = (const float*)d_in[9];
    const float* bp = (const float*)d_in[10];
    const float* Wv = (const float*)d_in[11];
    const float* bv = (const float*)d_in[12];

    char* ws = (char*)d_ws;
    __hip_bfloat16* W1b = (__hip_bfloat16*)(ws + 0);         // 2,097,152
    __hip_bfloat16* W2b = (__hip_bfloat16*)(ws + 2097152);   //   524,288
    __hip_bfloat16* Wgb = (__hip_bfloat16*)(ws + 2621440);   // 1,572,864
    __hip_bfloat16* z1b = (__hip_bfloat16*)(ws + 4194304);   // 8,388,608
    __hip_bfloat16* z2b = (__hip_bfloat16*)(ws + 12582912);  // 8,388,608
    float*          Xb  = (float*)(ws + 20971520);           // 50,331,648
    float*          seq = (float*)(ws + 71303168);           // 16,777,216
    unsigned long long* hbuf = (unsigned long long*)(ws + 88080384); // 8,192
    // hbuf needs NO init: step tags are self-validating vs 0xAA poison.
    // ctl carved from z1b (dead after gemm2 reads it; init_ctl is
    // stream-ordered after the gemms, before scan) — zero extra ws footprint.
    int* ctl = (int*)(ws + 4194304);

    float* out = (float*)d_out;
    float* pol = out;
    float* val = out + (size_t)T_STEPS * AACT;
    float* hT  = out + (size_t)T_STEPS * AACT + T_STEPS;

    cast_f32_bf16<<<DIN * DD / 256, 256, 0, stream>>>(W1, W1b, DIN * DD);
    cast_f32_bf16<<<DD * DD / 256, 256, 0, stream>>>(W2, W2b, DD * DD);
    cast_f32_bf16<<<DD * H3 / 256, 256, 0, stream>>>(Wg, Wgb, DD * H3);

    dim3 blk(256);
    gemm_bf16<<<dim3(T_STEPS / 64, DD / 64), blk, 0, stream>>>(
        x, nullptr, W1b, b1, z1b, nullptr, T_STEPS, DD, DIN, 1);
    gemm_bf16<<<dim3(T_STEPS / 64, DD / 64), blk, 0, stream>>>(
        nullptr, z1b, W2b, b2, z2b, nullptr, T_STEPS, DD, DD, 1);
    gemm_bf16<<<dim3(T_STEPS / 64, H3 / 64), blk, 0, stream>>>(
        nullptr, z2b, Wgb, bg, nullptr, Xb, T_STEPS, H3, DD, 0);

    init_ctl<<<1, 1, 0, stream>>>(ctl);
    scan_kernel<<<NWG, 256, 0, stream>>>(Xb, Ug, bg, h0, seq, hbuf, hT, ctl);

    heads_kernel<<<T_STEPS, 64, 0, stream>>>(seq, Wp, bp, Wv, bv, pol, val);
}

// Round 6
// 12154.640 us; speedup vs baseline: 22.8367x; 1.0200x over previous
//
#include <hip/hip_runtime.h>
#include <hip/hip_bf16.h>

// Problem: T=8192 steps, D_IN=2048, D=512 dense, H=512 cell, A=18 actions.
// out = concat(policy [T,18], value [T,1], hT [1,512]) fp32, 156160 elems.
//
// R5: R4 proved compute-side model (DPP reduce = exactly -300cyc/step);
// remaining ~3100cyc/step is exchange latency. Two cuts, protocol unchanged:
// (1) __syncthreads drains vmcnt(0) -> publisher lanes stall each step on
//     their hbuf/seq store ACKs (~300-500cyc). Barrier only needs LDS
//     ordering: raw s_waitcnt lgkmcnt(0) + s_barrier keeps global ops
//     (X prefetch, publish stores, dangling polls) in flight.
// (2) dependent spin samples every L (~600cyc); dual poll chains staggered
//     ~L/2 via s_sleep halve the sampling quantum (vmcnt retires in issue
//     order -> checking chain A waits only A while B stays in flight).

#define T_STEPS 8192
#define DIN 2048
#define DD 512
#define HHH 512
#define AACT 18
#define H3 1536
#define NWG 32          // worker WGs; each owns 16 rows of h

typedef __attribute__((ext_vector_type(8))) short short8;
typedef __attribute__((ext_vector_type(4))) float f32x4;

// ---------------------------------------------------------------- casts
__global__ void cast_f32_bf16(const float* __restrict__ in,
                              __hip_bfloat16* __restrict__ out, int n)
{
    int i = blockIdx.x * 256 + threadIdx.x;
    if (i < n) out[i] = __float2bfloat16(in[i]);
}

// ctl[2] = global abort flag (dead-man). ctl[0..1] unused.
__global__ void init_ctl(int* ctl) { ctl[0] = 0; ctl[1] = 0; ctl[2] = 0; }

// ---------------------------------------------------------------- GEMM
// C[M,N] = act(A[M,K] @ B[K,N] + bias). A either fp32 (cast on stage) or bf16.
// Block 256 (4 waves), tile 64x64, K-tile 32.
// MFMA 16x16x32 bf16: D: col=lane&15, row=quad*4+reg (verified m89/m91).
__global__ __launch_bounds__(256) void gemm_bf16(
    const float* __restrict__ A32, const __hip_bfloat16* __restrict__ A16,
    const __hip_bfloat16* __restrict__ B, const float* __restrict__ bias,
    __hip_bfloat16* __restrict__ Cb, float* __restrict__ Cf,
    int M, int N, int K, int relu)
{
    const int m0 = blockIdx.x * 64;
    const int n0 = blockIdx.y * 64;
    const int t  = threadIdx.x;
    const int wave = t >> 6;
    const int lane = t & 63;
    const int quad = lane >> 4;
    const int l16  = lane & 15;

    __shared__ __align__(16) __hip_bfloat16 As[64 * 40];
    __shared__ __align__(16) __hip_bfloat16 Bs[64 * 40];

    f32x4 acc[4];
#pragma unroll
    for (int c = 0; c < 4; ++c) acc[c] = (f32x4){0.f, 0.f, 0.f, 0.f};

    const int ar = t >> 2, akc = (t & 3) * 8;
    const int bk = t >> 3, bn  = (t & 7) * 8;

    for (int kb = 0; kb < K; kb += 32) {
        if (A32) {
            const float* src = A32 + (size_t)(m0 + ar) * K + kb + akc;
            float4 f0 = *(const float4*)(src);
            float4 f1 = *(const float4*)(src + 4);
            union { short8 v; __hip_bfloat16 h[8]; } u;
            u.h[0] = __float2bfloat16(f0.x); u.h[1] = __float2bfloat16(f0.y);
            u.h[2] = __float2bfloat16(f0.z); u.h[3] = __float2bfloat16(f0.w);
            u.h[4] = __float2bfloat16(f1.x); u.h[5] = __float2bfloat16(f1.y);
            u.h[6] = __float2bfloat16(f1.z); u.h[7] = __float2bfloat16(f1.w);
            *(short8*)&As[ar * 40 + akc] = u.v;
        } else {
            const __hip_bfloat16* src = A16 + (size_t)(m0 + ar) * K + kb + akc;
            *(short8*)&As[ar * 40 + akc] = *(const short8*)src;
        }
        {
            const __hip_bfloat16* src = B + (size_t)(kb + bk) * N + n0 + bn;
            short8 v = *(const short8*)src;
            const __hip_bfloat16* vh = (const __hip_bfloat16*)&v;
#pragma unroll
            for (int i = 0; i < 8; ++i) Bs[(bn + i) * 40 + bk] = vh[i];
        }
        __syncthreads();

        short8 a = *(const short8*)&As[(wave * 16 + l16) * 40 + quad * 8];
#pragma unroll
        for (int c = 0; c < 4; ++c) {
            short8 b = *(const short8*)&Bs[(c * 16 + l16) * 40 + quad * 8];
            acc[c] = __builtin_amdgcn_mfma_f32_16x16x32_bf16(a, b, acc[c], 0, 0, 0);
        }
        __syncthreads();
    }

#pragma unroll
    for (int c = 0; c < 4; ++c) {
        const int col = n0 + c * 16 + l16;
        const float bb = bias ? bias[col] : 0.f;
#pragma unroll
        for (int r = 0; r < 4; ++r) {
            const int row = m0 + wave * 16 + quad * 4 + r;
            float v = acc[c][r] + bb;
            if (relu) v = fmaxf(v, 0.f);
            if (Cb) Cb[(size_t)row * N + col] = __float2bfloat16(v);
            if (Cf) Cf[(size_t)row * N + col] = v;
        }
    }
}

// --------------------------------------------------------------- DPP reduce
// Reduce-to-lane0 within each 16-lane row via row_shl:N — lane i reads lane
// i+N; reads past the row end are 0-filled (bound_ctrl=true). Verified R3/R4.
template <int CTRL>
__device__ __forceinline__ float dpp_red_add(float x)
{
    int sh = __builtin_amdgcn_update_dpp(0, __float_as_int(x), CTRL, 0xF, 0xF, true);
    return x + __int_as_float(sh);
}

// LDS-only barrier: orders ds ops (lgkmcnt) but deliberately does NOT drain
// vmcnt — global loads (X prefetch, dangling polls) and stores (hbuf publish,
// seq) stay in flight across the barrier. __syncthreads would emit
// s_waitcnt vmcnt(0) and stall publishers on their own store ACKs each step.
__device__ __forceinline__ void wg_barrier_lds_only()
{
    asm volatile("s_waitcnt lgkmcnt(0)" ::: "memory");
    __builtin_amdgcn_s_barrier();
    asm volatile("" ::: "memory");
}

// ---------------------------------------------------------------- GRU scan
// 32 persistent WGs x 256 threads (waves_per_eu(1,1): WG alone on its CU).
// WG i owns h rows [16i, 16i+16). Thread t: jl=t>>4 (row), kp=t&15
// (k-chunk [32kp, 32kp+32)).
// h exchange (device scope, PROVEN): 8B tagged slots {f32 val, u32 step},
// double-buffered by step parity, RELAXED AGENT atomics, compiler-exact
// vmcnt counting. Spin uses TWO staggered sample chains (A/B ~L/2 apart):
// vmcnt retires oldest-first, so checking A waits only A while B is in
// flight; steady-state alternation keeps samples ~L/2 apart, halving the
// detection quantum. Per-slot tags stay self-validating in both chains.
__global__ __launch_bounds__(256)
__attribute__((amdgpu_waves_per_eu(1, 1)))
void scan_kernel(
    const float* __restrict__ X,            // [T][1536] = z@Wg + bg[0]
    const float* __restrict__ Ug,           // [512][1536]
    const float* __restrict__ bg,           // [2][1536]; row 1 = recurrent bias
    const float* __restrict__ h0,           // [512] prev_hidden
    float* __restrict__ seq,                // [T][512]
    unsigned long long* __restrict__ hbuf,  // [2][512] tagged h (no init needed)
    float* __restrict__ hT,                 // [512] -> d_out tail
    int* __restrict__ ctl)                  // ctl[2] = abort flag
{
    const int t  = threadIdx.x;
    const int wg = blockIdx.x;
    const int jl = t >> 4;
    const int kp = t & 15;
    const int j  = wg * 16 + jl;
    const int k0 = kp * 32;

    // double-buffered h stage; row stride 36 words = 144B (16B aligned;
    // b128 reads across 16 kp-lanes alias banks 2-way = free per m136)
    __shared__ __align__(16) float h_lds[2][16 * 36];
    __shared__ int wg_abort;
    if (t == 0) wg_abort = 0;

    float wz[32], wr[32], wh[32];
#pragma unroll
    for (int m = 0; m < 32; ++m) {
        const float* row = Ug + (size_t)(k0 + m) * H3;
        wz[m] = row[j];
        wr[m] = row[512 + j];
        wh[m] = row[1024 + j];
    }
    // pin all 96 weights into AGPRs: guaranteed register residency for the
    // whole step loop (no scratch spill path exists for "a"-pinned values)
#pragma unroll
    for (int m = 0; m < 32; ++m) {
        asm volatile("" : "+a"(wz[m]), "+a"(wr[m]), "+a"(wh[m]));
    }

    const float* brec = bg + H3;
    const float bz = brec[j], brr = brec[512 + j], bh = brec[1024 + j];
    float hj = h0[j];  // my h element (kp==0 lanes)

    // staging slots for this thread (thread t owns k1, k2)
    const int k1 = t, k2 = t + 256;
    const int la1 = (k1 >> 5) * 36 + (k1 & 31);
    const int la2 = (k2 >> 5) * 36 + (k2 & 31);

    // prefetch X[0]
    float xz = 0.f, xr = 0.f, xh = 0.f;
    if (kp == 0) { xz = X[j]; xr = X[512 + j]; xh = X[1024 + j]; }

    for (int s = 0; s < T_STEPS; ++s) {
        float* hl = h_lds[s & 1];

        // ---- prefetch X[s+1] FIRST: retires under the spin (no vmcnt
        // drain anywhere in the loop keeps these in flight throughout)
        float nxz = 0.f, nxr = 0.f, nxh = 0.f;
        if (kp == 0 && s + 1 < T_STEPS) {
            const float* Xs = X + (size_t)(s + 1) * H3;
            nxz = Xs[j]; nxr = Xs[512 + j]; nxh = Xs[1024 + j];
        }

        // ---- acquire h_s: dual staggered sample chains on tagged slots
        if (s == 0) {
            hl[la1] = h0[k1];
            hl[la2] = h0[k2];
        } else {
            const unsigned long long* src = hbuf + ((size_t)(s & 1) << 9);
            unsigned long long v1 = 0, v2 = 0;
            // chain A sample
            unsigned long long a1 = __hip_atomic_load(src + k1, __ATOMIC_RELAXED, __HIP_MEMORY_SCOPE_AGENT);
            unsigned long long a2 = __hip_atomic_load(src + k2, __ATOMIC_RELAXED, __HIP_MEMORY_SCOPE_AGENT);
            // ~L/2 stagger so A/B sample the slot out of phase
            asm volatile("" ::: "memory");
            __builtin_amdgcn_s_sleep(4);          // ~256 cyc
            asm volatile("" ::: "memory");
            // chain B sample
            unsigned long long b1 = __hip_atomic_load(src + k1, __ATOMIC_RELAXED, __HIP_MEMORY_SCOPE_AGENT);
            unsigned long long b2 = __hip_atomic_load(src + k2, __ATOMIC_RELAXED, __HIP_MEMORY_SCOPE_AGENT);
            bool ok1 = false, ok2 = false;
            int guard = 0;
            for (;;) {
                // phase A: consume chain-A sample (waits A only; B in flight)
                if (!ok1 && (unsigned)(a1 >> 32) == (unsigned)s) { v1 = a1; ok1 = true; }
                if (!ok2 && (unsigned)(a2 >> 32) == (unsigned)s) { v2 = a2; ok2 = true; }
                if (ok1 && ok2) break;
                if (!ok1) a1 = __hip_atomic_load(src + k1, __ATOMIC_RELAXED, __HIP_MEMORY_SCOPE_AGENT);
                if (!ok2) a2 = __hip_atomic_load(src + k2, __ATOMIC_RELAXED, __HIP_MEMORY_SCOPE_AGENT);
                // phase B: consume chain-B sample (~L/2 later)
                if (!ok1 && (unsigned)(b1 >> 32) == (unsigned)s) { v1 = b1; ok1 = true; }
                if (!ok2 && (unsigned)(b2 >> 32) == (unsigned)s) { v2 = b2; ok2 = true; }
                if (ok1 && ok2) break;
                if (!ok1) b1 = __hip_atomic_load(src + k1, __ATOMIC_RELAXED, __HIP_MEMORY_SCOPE_AGENT);
                if (!ok2) b2 = __hip_atomic_load(src + k2, __ATOMIC_RELAXED, __HIP_MEMORY_SCOPE_AGENT);
                if ((++guard & 511) == 0) {        // dead-man / global abort
                    int ab = __hip_atomic_load(ctl + 2, __ATOMIC_RELAXED,
                                               __HIP_MEMORY_SCOPE_AGENT);
                    if (ab || guard > (1 << 16)) {
                        wg_abort = 1;
                        __hip_atomic_store(ctl + 2, 1, __ATOMIC_RELAXED,
                                           __HIP_MEMORY_SCOPE_AGENT);
                        break;
                    }
                }
            }
            hl[la1] = __uint_as_float((unsigned)v1);
            hl[la2] = __uint_as_float((unsigned)v2);
        }
        wg_barrier_lds_only();
        if (wg_abort) return;   // uniform exit: no barrier divergence

        // ---- partial matvec: 32 k-values x 3 gate columns
        float accz = 0.f, accr = 0.f, acch = 0.f;
        const float* hb = &hl[kp * 36];
#pragma unroll
        for (int m = 0; m < 32; m += 4) {
            float4 hv = *(const float4*)(hb + m);
            accz = fmaf(hv.x, wz[m    ], accz);
            accz = fmaf(hv.y, wz[m + 1], accz);
            accz = fmaf(hv.z, wz[m + 2], accz);
            accz = fmaf(hv.w, wz[m + 3], accz);
            accr = fmaf(hv.x, wr[m    ], accr);
            accr = fmaf(hv.y, wr[m + 1], accr);
            accr = fmaf(hv.z, wr[m + 2], accr);
            accr = fmaf(hv.w, wr[m + 3], accr);
            acch = fmaf(hv.x, wh[m    ], acch);
            acch = fmaf(hv.y, wh[m + 1], acch);
            acch = fmaf(hv.z, wh[m + 2], acch);
            acch = fmaf(hv.w, wh[m + 3], acch);
        }
        // reduce across the 16 kp lanes: VALU-only DPP row_shl tree,
        // sum accumulates INTO lane 0 of each 16-lane row (= kp==0)
        accz = dpp_red_add<0x108>(accz);  // += lane+8
        accr = dpp_red_add<0x108>(accr);
        acch = dpp_red_add<0x108>(acch);
        accz = dpp_red_add<0x104>(accz);  // += lane+4
        accr = dpp_red_add<0x104>(accr);
        acch = dpp_red_add<0x104>(acch);
        accz = dpp_red_add<0x102>(accz);  // += lane+2
        accr = dpp_red_add<0x102>(accr);
        acch = dpp_red_add<0x102>(acch);
        accz = dpp_red_add<0x101>(accz);  // += lane+1
        accr = dpp_red_add<0x101>(accr);
        acch = dpp_red_add<0x101>(acch);

        if (kp == 0) {
            const float rz = accz + bz, rr = accr + brr, rh = acch + bh;
            const float zt = 1.f / (1.f + __expf(-(xz + rz)));
            const float rt = 1.f / (1.f + __expf(-(xr + rr)));
            const float hc = 1.f / (1.f + __expf(-(xh + rt * rh)));
            const float hn = zt * hj + (1.f - zt) * hc;
            hj = hn;
            // publish FIRST and IMMEDIATELY: this store is the device-wide
            // critical path (no pairing shuffle before it)
            unsigned long long pk =
                ((unsigned long long)(unsigned)(s + 1) << 32) | (unsigned)__float_as_uint(hn);
            __hip_atomic_store(hbuf + (size_t)(((s + 1) & 1) << 9) + j, pk,
                               __ATOMIC_RELAXED, __HIP_MEMORY_SCOPE_AGENT);
            seq[(size_t)s * HHH + j] = hn;
            if (s == T_STEPS - 1) hT[j] = hn;
        }
        xz = nxz; xr = nxr; xh = nxh;
        // no trailing barrier: LDS double-buffered; next iter syncs after stage
    }
}

// ---------------------------------------------------------------- heads
__global__ __launch_bounds__(64) void heads_kernel(
    const float* __restrict__ seq, const float* __restrict__ Wp,
    const float* __restrict__ bp, const float* __restrict__ Wv,
    const float* __restrict__ bv, float* __restrict__ pol,
    float* __restrict__ val)
{
    const int s = blockIdx.x;
    const int l = threadIdx.x;
    const float* h = seq + (size_t)s * HHH;

    float acc[19];
#pragma unroll
    for (int jj = 0; jj < 19; ++jj) acc[jj] = 0.f;

#pragma unroll
    for (int kk = 0; kk < 8; ++kk) {
        const int k = kk * 64 + l;
        const float hv = h[k];
        const float* wrow = Wp + (size_t)k * AACT;
#pragma unroll
        for (int jj = 0; jj < AACT; ++jj) acc[jj] = fmaf(hv, wrow[jj], acc[jj]);
        acc[18] = fmaf(hv, Wv[k], acc[18]);
    }
#pragma unroll
    for (int jj = 0; jj < 19; ++jj) {
        float v = acc[jj];
#pragma unroll
        for (int off = 32; off; off >>= 1) v += __shfl_down(v, off, 64);
        acc[jj] = v;
    }
    if (l == 0) {
        float lg[18], mx = -1e30f;
#pragma unroll
        for (int jj = 0; jj < AACT; ++jj) { lg[jj] = acc[jj] + bp[jj]; mx = fmaxf(mx, lg[jj]); }
        float sum = 0.f;
#pragma unroll
        for (int jj = 0; jj < AACT; ++jj) { lg[jj] = __expf(lg[jj] - mx); sum += lg[jj]; }
        const float inv = 1.f / sum;
#pragma unroll
        for (int jj = 0; jj < AACT; ++jj) pol[(size_t)s * AACT + jj] = lg[jj] * inv;
        val[s] = acc[18] + bv[0];
    }
}

// ---------------------------------------------------------------- launch
extern "C" void kernel_launch(void* const* d_in, const int* in_sizes, int n_in,
                              void* d_out, int out_size, void* d_ws, size_t ws_size,
                              hipStream_t stream)
{
    const float* x  = (const float*)d_in[0];
    const float* h0 = (const float*)d_in[1];
    const float* W1 = (const float*)d_in[2];
    const float* b1 = (const float*)d_in[3];
    const float* W2 = (const float*)d_in[4];
    const float* b2 = (const float*)d_in[5];
    const float* Wg = (const float*)d_in[6];
    const float* Ug = (const float*)d_in[7];
    const float* bg = (const float*)d_in[8];
    const float* Wp = (const float*)d_in[9];
    const float* bp = (const float*)d_in[10];
    const float* Wv = (const float*)d_in[11];
    const float* bv = (const float*)d_in[12];

    char* ws = (char*)d_ws;
    __hip_bfloat16* W1b = (__hip_bfloat16*)(ws + 0);         // 2,097,152
    __hip_bfloat16* W2b = (__hip_bfloat16*)(ws + 2097152);   //   524,288
    __hip_bfloat16* Wgb = (__hip_bfloat16*)(ws + 2621440);   // 1,572,864
    __hip_bfloat16* z1b = (__hip_bfloat16*)(ws + 4194304);   // 8,388,608
    __hip_bfloat16* z2b = (__hip_bfloat16*)(ws + 12582912);  // 8,388,608
    float*          Xb  = (float*)(ws + 20971520);           // 50,331,648
    float*          seq = (float*)(ws + 71303168);           // 16,777,216
    unsigned long long* hbuf = (unsigned long long*)(ws + 88080384); // 8,192
    // hbuf needs NO init: step tags are self-validating vs 0xAA poison.
    // ctl carved from z1b (dead after gemm2 reads it; init_ctl is
    // stream-ordered after the gemms, before scan) — zero extra ws footprint.
    int* ctl = (int*)(ws + 4194304);

    float* out = (float*)d_out;
    float* pol = out;
    float* val = out + (size_t)T_STEPS * AACT;
    float* hT  = out + (size_t)T_STEPS * AACT + T_STEPS;

    cast_f32_bf16<<<DIN * DD / 256, 256, 0, stream>>>(W1, W1b, DIN * DD);
    cast_f32_bf16<<<DD * DD / 256, 256, 0, stream>>>(W2, W2b, DD * DD);
    cast_f32_bf16<<<DD * H3 / 256, 256, 0, stream>>>(Wg, Wgb, DD * H3);

    dim3 blk(256);
    gemm_bf16<<<dim3(T_STEPS / 64, DD / 64), blk, 0, stream>>>(
        x, nullptr, W1b, b1, z1b, nullptr, T_STEPS, DD, DIN, 1);
    gemm_bf16<<<dim3(T_STEPS / 64, DD / 64), blk, 0, stream>>>(
        nullptr, z1b, W2b, b2, z2b, nullptr, T_STEPS, DD, DD, 1);
    gemm_bf16<<<dim3(T_STEPS / 64, H3 / 64), blk, 0, stream>>>(
        nullptr, z2b, Wgb, bg, nullptr, Xb, T_STEPS, H3, DD, 0);

    init_ctl<<<1, 1, 0, stream>>>(ctl);
    scan_kernel<<<NWG, 256, 0, stream>>>(Xb, Ug, bg, h0, seq, hbuf, hT, ctl);

    heads_kernel<<<T_STEPS, 64, 0, stream>>>(seq, Wp, bp, Wv, bv, pol, val);
}